// Round 14
// baseline (51.427 us; speedup 1.0000x reference)
//
#include <hip/hip_runtime.h>

#define NSUB 16
#define MM 20
#define NFILT 2000
#define TRI (MM*(MM+1)/2)
#define GR 250           // rows per block / scan-group size (2000 = 8 groups)

// params published by setup kernel, consumed by later kernels (same-stream order)
__device__ __align__(16) float g_mu[32];
__device__ __align__(16) float g_W[16];
__device__ __align__(16) float g_Th[16];
__device__ float g_Vo;

__device__ __forceinline__ float ftanh(float x) {
  x = fminf(10.f, fmaxf(-10.f, x));
  float e = __expf(2.f * x);
  return (e - 1.f) * __builtin_amdgcn_rcpf(e + 1.f);
}

__device__ __forceinline__ float rfl(float v) {
  return __int_as_float(__builtin_amdgcn_readfirstlane(__float_as_int(v)));
}

__device__ __forceinline__ float f4c(const float4& v, int c) {
  return c == 0 ? v.x : c == 1 ? v.y : c == 2 ? v.z : v.w;
}

// full wave64 inclusive add-scan, pure VALU DPP (HW-validated R2-R13)
__device__ __forceinline__ float wave_incl_scan(float x) {
  float t;
  t = __int_as_float(__builtin_amdgcn_update_dpp(0, __float_as_int(x), 0x111, 0xf, 0xf, true)); x += t;
  t = __int_as_float(__builtin_amdgcn_update_dpp(0, __float_as_int(x), 0x112, 0xf, 0xf, true)); x += t;
  t = __int_as_float(__builtin_amdgcn_update_dpp(0, __float_as_int(x), 0x114, 0xf, 0xf, true)); x += t;
  t = __int_as_float(__builtin_amdgcn_update_dpp(0, __float_as_int(x), 0x118, 0xf, 0xf, true)); x += t;
  t = __int_as_float(__builtin_amdgcn_update_dpp(0, __float_as_int(x), 0x142, 0xa, 0xf, true)); x += t; // bcast15
  t = __int_as_float(__builtin_amdgcn_update_dpp(0, __float_as_int(x), 0x143, 0xc, 0xf, true)); x += t; // bcast31
  return x;
}

// ---------------------------------------------------------------------------
// Setup: one 64-thread block per subunit; register-column Gauss-Jordan.
// (Validated R5-R13.)
// ---------------------------------------------------------------------------
__global__ void __launch_bounds__(64)
k_setup(const float* alpha_log, const float* beta_p, const float* gamma_log,
        const float* kvlog, const float* mean_u, const float* su_low,
        const float* u_in, const float* W_log, const float* V_o_p,
        const float* Theta, float* out, int T)
{
  const int s = blockIdx.x;       // 0..31
  const int lane = threadIdx.x;   // 0..63

  const float alpha = __expf(alpha_log[s]);
  const float beta  = beta_p[s];
  const float gamma = __expf(gamma_log[s]);
  const float kv    = __expf(kvlog[s]);
  const float fs    = (float)s;

  const long long OFF_MEANU = T;
  const long long OFF_SU    = (long long)T + 640;
  const long long OFF_COV   = (long long)T + 640 + 12800;
  const long long OFF_INV   = (long long)T + 640 + 2*12800;
  const long long OFF_FE    = (long long)T + 640 + 3*12800;
  const long long OFF_FI    = OFF_FE + 32000;
  const long long OFF_UIN   = OFF_FI + 32000;

  float urv[MM], t1v[MM], rv_[MM];
#pragma unroll
  for (int i = 0; i < MM; ++i) {
    float u = u_in[s*MM + i];
    urv[i] = u;
    t1v[i] = alpha * (u - beta) * (u - beta);
    rv_[i] = kv * __expf(-alpha*(fs-beta)*(fs-beta) - gamma*(fs-u)*(fs-u) - t1v[i]);
  }

  const bool cL = lane < MM;
  const bool cR = lane >= MM && lane < 2*MM;
  const float u_l = u_in[s*MM + (cL ? lane : 0)];
  const float t1_l = alpha * (u_l - beta) * (u_l - beta);

  float col[MM];
#pragma unroll
  for (int i = 0; i < MM; ++i) {
    float du = urv[i] - u_l;
    float cv = kv * __expf(-t1v[i] - gamma*du*du - t1_l);
    float idv = (lane - MM == i) ? 1.f : 0.f;
    col[i] = cL ? cv : (cR ? idv : 0.f);
    if (cL) out[OFF_COV + (long long)s*400 + i*MM + lane] = cv;
  }

#pragma unroll
  for (int k = 0; k < MM; ++k) {
    float fc[MM];
#pragma unroll
    for (int i = 0; i < MM; ++i)
      fc[i] = __int_as_float(__builtin_amdgcn_readlane(__float_as_int(col[i]), k));
    const float pr = 1.0f / fc[k];
    col[k] *= pr;
#pragma unroll
    for (int i = 0; i < MM; ++i)
      if (i != k) col[i] = fmaf(-fc[i], col[k], col[i]);
  }

  if (cR) {
    const int t = lane - MM;
#pragma unroll
    for (int i = 0; i < MM; ++i)
      out[OFF_INV + (long long)s*400 + i*MM + t] = col[i];
  }

  float dotr = 0.f;
#pragma unroll
  for (int i = 0; i < MM; ++i) dotr += rv_[i] * col[i];
  float mpart = cR ? dotr * mean_u[s*MM + (lane - MM)] : 0.f;
  float mu = mpart;
#pragma unroll
  for (int o = 1; o < 64; o <<= 1) mu += __shfl_xor(mu, o, 64);
  mu = rfl(mu);
  if (lane == 0) g_mu[s] = mu;

  __shared__ float Lm[MM][MM];
  for (int c = lane; c < MM*MM; c += 64) Lm[c/MM][c%MM] = 0.f;
  __syncthreads();
  for (int k = lane; k < TRI; k += 64) {
    int i = (int)((sqrtf(8.f*(float)k + 1.f) - 1.f) * 0.5f);
    while ((i+1)*(i+2)/2 <= k) ++i;
    while (i*(i+1)/2 > k) --i;
    int jx = k - i*(i+1)/2;
    Lm[i][jx] = su_low[s*TRI + k];
  }
  __syncthreads();
  for (int c = lane; c < MM*MM; c += 64) {
    int i = c / MM, kk = c % MM;
    float acc = 0.f;
#pragma unroll
    for (int jx = 0; jx < MM; ++jx) acc += Lm[i][jx] * Lm[kk][jx];
    out[OFF_SU + (long long)s*400 + c] = acc;
  }

  if (cL) {
    out[OFF_MEANU + s*MM + lane] = mean_u[s*MM + lane];
    out[OFF_UIN  + s*MM + lane] = u_l;
  }

  {
    long long base = (s < NSUB) ? (OFF_FE + (long long)s*NFILT)
                                : (OFF_FI + (long long)(s - NSUB)*NFILT);
    float2 f2 = make_float2(mu, mu);
    float2* dst = (float2*)(out + base);
    for (int n = lane; n < NFILT/2; n += 64) dst[n] = f2;
  }

  if (s == 0) {
    if (lane < 16) {
      g_W[lane]  = __expf(W_log[lane]);
      g_Th[lane] = Theta[lane];
    }
    if (lane == 0) g_Vo = V_o_p[0];
  }
}

// ---------------------------------------------------------------------------
// k_scan: 2000 blocks x 256 threads. DENSE float4 loads (fi = 256k + tid),
// mu-fold per fixed quarter (tid&3), LDS bounce ([256][17]-padded, 2-way max),
// row-per-thread DPP scan + cross-wave prefix; stores packed as float4 to
// 4 channel-planes St4[q][T] -> 1 KB per wave store instruction.
// ---------------------------------------------------------------------------
__global__ void __launch_bounds__(256, 8)
k_scan(const float4* __restrict__ E4, const float4* __restrict__ I4,
       float4* __restrict__ St4, float* __restrict__ G, int T)
{
  __shared__ float tile[256*17 + 4];
  __shared__ float wred[4][16];
  const int tid  = threadIdx.x;    // 0..255
  const int lane = tid & 63;
  const int w    = tid >> 6;       // 0..3
  const int qg   = tid & 3;        // this thread's channel quarter
  const int b    = blockIdx.x;

  const float4 mue4 = *(const float4*)&g_mu[4*qg];
  const float4 mui4 = *(const float4*)&g_mu[16 + 4*qg];
  const float4 z4 = make_float4(0.f, 0.f, 0.f, 0.f);

  const long long base4 = (long long)b * (GR*4);   // float4 index of block start
  const long long q4tot = (long long)T * 4;

  // dense loads, all issued up front
  float4 ebuf[4], ibuf[4];
#pragma unroll
  for (int k = 0; k < 4; ++k) {
    const int fi = 256*k + tid;
    const long long gq = base4 + fi;
    const bool a = (fi < GR*4) && (gq < q4tot);
    ebuf[k] = a ? E4[gq] : z4;
    ibuf[k] = a ? I4[gq] : z4;
  }
  // fold + LDS tile writes (b32, stride-17 rows)
#pragma unroll
  for (int k = 0; k < 4; ++k) {
    const int fi = 256*k + tid;
    const int row = fi >> 2;         // 0..255
    float* dst = &tile[row*17 + 4*qg];
    dst[0] = mue4.x*ebuf[k].x + mui4.x*ibuf[k].x;
    dst[1] = mue4.y*ebuf[k].y + mui4.y*ibuf[k].y;
    dst[2] = mue4.z*ebuf[k].z + mui4.z*ibuf[k].z;
    dst[3] = mue4.w*ebuf[k].w + mui4.w*ibuf[k].w;
  }
  __syncthreads();

  // row-per-thread: 16 conflict-free b32 reads (stride 17 bijective mod 32),
  // then per-channel full-wave DPP scans
  float inc[16];
#pragma unroll
  for (int c = 0; c < 16; ++c) {
    inc[c] = wave_incl_scan(tile[tid*17 + c]);
    if (lane == 63) wred[w][c] = inc[c];
  }
  __syncthreads();

  // cross-wave exclusive prefix (LDS broadcast reads)
  float sv[16];
#pragma unroll
  for (int q = 0; q < 4; ++q) {
    float ox = 0.f, oy = 0.f, oz = 0.f, ow = 0.f;
#pragma unroll
    for (int wp = 0; wp < 3; ++wp) {
      if (wp < w) {
        const float4 t = *(const float4*)&wred[wp][4*q];
        ox += t.x; oy += t.y; oz += t.z; ow += t.w;
      }
    }
    sv[4*q]   = inc[4*q]   + ox;
    sv[4*q+1] = inc[4*q+1] + oy;
    sv[4*q+2] = inc[4*q+2] + oz;
    sv[4*q+3] = inc[4*q+3] + ow;
  }

  // packed stores: plane q holds channels 4q..4q+3; lane-consecutive rows
  const long long r = (long long)b*GR + tid;
  if ((tid < GR) && (r < T)) {
#pragma unroll
    for (int q = 0; q < 4; ++q)
      St4[(long long)q*T + r] = make_float4(sv[4*q], sv[4*q+1], sv[4*q+2], sv[4*q+3]);
  }

  if (tid < 16) {
    float a = 0.f;
#pragma unroll
    for (int wp = 0; wp < 4; ++wp) a += wred[wp][tid];
    G[b*16 + tid] = a;
  }
}

// ---------------------------------------------------------------------------
// k_volt: pure elementwise, row-per-thread. d = St4[q][r] - St4[q][r-2000],
// 8 dense float4 loads (L2-local: blocks b and b-8 share b%8 -> same XCD).
// Base table from G, tanh chain, dense store.
// ---------------------------------------------------------------------------
__global__ void __launch_bounds__(256, 8)
k_volt(const float4* __restrict__ St4, const float* __restrict__ G,
       float* __restrict__ out, int T)
{
  __shared__ float bs0[16];
  const int tid = threadIdx.x;     // 0..255
  const int b   = blockIdx.x;
  const long long r = (long long)b*GR + tid;
  const bool act = (tid < GR) && (r < T);
  const long long l = r - NFILT;
  const bool vl = act && (l >= 0);

  if (tid < 16) {
    float a = g_Th[tid];
#pragma unroll
    for (int gg = 0; gg < 8; ++gg) {
      const int gi = b - 8 + gg;
      if (gi >= 0) a += G[gi*16 + tid];
    }
    bs0[tid] = a;
  }

  const float4 z4 = make_float4(0.f, 0.f, 0.f, 0.f);
  float d[16];
#pragma unroll
  for (int q = 0; q < 4; ++q) {
    const long long pb = (long long)q * T;
    const float4 cu = act ? St4[pb + r] : z4;
    const float4 lg = vl  ? St4[pb + l] : z4;
    d[4*q]   = cu.x - lg.x;
    d[4*q+1] = cu.y - lg.y;
    d[4*q+2] = cu.z - lg.z;
    d[4*q+3] = cu.w - lg.w;
  }
  __syncthreads();

  float wk[16];
#pragma unroll
  for (int k = 0; k < 16; ++k) wk[k] = rfl(g_W[k]);
  const float Vo = rfl(g_Vo);

  float Wv[16];
#pragma unroll
  for (int q = 0; q < 4; ++q) {
    const float4 bsq = *(const float4*)&bs0[4*q];
    Wv[4*q]   = bsq.x + d[4*q];
    Wv[4*q+1] = bsq.y + d[4*q+1];
    Wv[4*q+2] = bsq.z + d[4*q+2];
    Wv[4*q+3] = bsq.w + d[4*q+3];
  }

  float v = ftanh(Wv[15]);
#pragma unroll
  for (int idx = 14; idx >= 0; --idx)
    v = ftanh(Wv[idx] + wk[idx + 1] * v);

  if (act) out[r] = v * wk[0] + Vo;
}

extern "C" void kernel_launch(void* const* d_in, const int* in_sizes, int n_in,
                              void* d_out, int out_size, void* d_ws, size_t ws_size,
                              hipStream_t stream) {
  const float* S_e       = (const float*)d_in[0];
  const float* S_i       = (const float*)d_in[1];
  const float* alpha_log = (const float*)d_in[2];
  const float* beta      = (const float*)d_in[3];
  const float* gamma_log = (const float*)d_in[4];
  const float* kvlog     = (const float*)d_in[5];
  const float* mean_u    = (const float*)d_in[6];
  const float* su_low    = (const float*)d_in[7];
  const float* u_in      = (const float*)d_in[8];
  const float* W_log     = (const float*)d_in[9];
  const float* V_o       = (const float*)d_in[10];
  const float* Theta     = (const float*)d_in[11];
  (void)n_in; (void)out_size; (void)ws_size;

  int T = in_sizes[0] / NSUB;
  const int nG = (T + GR - 1) / GR;

  // d_ws layout: St4 (4 planes x T float4 = 64 B/row) then G (nG x 16 f32)
  float4* St4 = (float4*)d_ws;
  float* G    = (float*)((char*)d_ws + (size_t)T * 64);
  float* out  = (float*)d_out;

  hipLaunchKernelGGL(k_setup, dim3(32), dim3(64), 0, stream,
                     alpha_log, beta, gamma_log, kvlog, mean_u, su_low, u_in,
                     W_log, V_o, Theta, out, T);
  hipLaunchKernelGGL(k_scan, dim3(nG), dim3(256), 0, stream,
                     (const float4*)S_e, (const float4*)S_i, St4, G, T);
  hipLaunchKernelGGL(k_volt, dim3(nG), dim3(256), 0, stream,
                     (const float4*)St4, G, out, T);
}

// Round 15
// 44.853 us; speedup vs baseline: 1.1466x; 1.1466x over previous
//
#include <hip/hip_runtime.h>

#define NSUB 16
#define MM 20
#define NFILT 2000
#define TRI (MM*(MM+1)/2)
#define GR 250           // rows per block / scan-group size (2000 = 8 groups)

// params published by setup kernel, consumed by later kernels (same-stream order)
__device__ __align__(16) float g_mu[32];
__device__ __align__(16) float g_W[16];
__device__ __align__(16) float g_Th[16];
__device__ float g_Vo;

__device__ __forceinline__ float ftanh(float x) {
  x = fminf(10.f, fmaxf(-10.f, x));
  float e = __expf(2.f * x);
  return (e - 1.f) * __builtin_amdgcn_rcpf(e + 1.f);
}

__device__ __forceinline__ float rfl(float v) {
  return __int_as_float(__builtin_amdgcn_readfirstlane(__float_as_int(v)));
}

__device__ __forceinline__ float f4c(const float4& v, int c) {
  return c == 0 ? v.x : c == 1 ? v.y : c == 2 ? v.z : v.w;
}

// full wave64 inclusive add-scan, pure VALU DPP (HW-validated R2-R13)
__device__ __forceinline__ float wave_incl_scan(float x) {
  float t;
  t = __int_as_float(__builtin_amdgcn_update_dpp(0, __float_as_int(x), 0x111, 0xf, 0xf, true)); x += t;
  t = __int_as_float(__builtin_amdgcn_update_dpp(0, __float_as_int(x), 0x112, 0xf, 0xf, true)); x += t;
  t = __int_as_float(__builtin_amdgcn_update_dpp(0, __float_as_int(x), 0x114, 0xf, 0xf, true)); x += t;
  t = __int_as_float(__builtin_amdgcn_update_dpp(0, __float_as_int(x), 0x118, 0xf, 0xf, true)); x += t;
  t = __int_as_float(__builtin_amdgcn_update_dpp(0, __float_as_int(x), 0x142, 0xa, 0xf, true)); x += t; // bcast15
  t = __int_as_float(__builtin_amdgcn_update_dpp(0, __float_as_int(x), 0x143, 0xc, 0xf, true)); x += t; // bcast31
  return x;
}

// ---------------------------------------------------------------------------
// Setup: one 64-thread block per subunit; register-column Gauss-Jordan.
// (Validated R5-R14.)
// ---------------------------------------------------------------------------
__global__ void __launch_bounds__(64)
k_setup(const float* alpha_log, const float* beta_p, const float* gamma_log,
        const float* kvlog, const float* mean_u, const float* su_low,
        const float* u_in, const float* W_log, const float* V_o_p,
        const float* Theta, float* out, int T)
{
  const int s = blockIdx.x;       // 0..31
  const int lane = threadIdx.x;   // 0..63

  const float alpha = __expf(alpha_log[s]);
  const float beta  = beta_p[s];
  const float gamma = __expf(gamma_log[s]);
  const float kv    = __expf(kvlog[s]);
  const float fs    = (float)s;

  const long long OFF_MEANU = T;
  const long long OFF_SU    = (long long)T + 640;
  const long long OFF_COV   = (long long)T + 640 + 12800;
  const long long OFF_INV   = (long long)T + 640 + 2*12800;
  const long long OFF_FE    = (long long)T + 640 + 3*12800;
  const long long OFF_FI    = OFF_FE + 32000;
  const long long OFF_UIN   = OFF_FI + 32000;

  float urv[MM], t1v[MM], rv_[MM];
#pragma unroll
  for (int i = 0; i < MM; ++i) {
    float u = u_in[s*MM + i];
    urv[i] = u;
    t1v[i] = alpha * (u - beta) * (u - beta);
    rv_[i] = kv * __expf(-alpha*(fs-beta)*(fs-beta) - gamma*(fs-u)*(fs-u) - t1v[i]);
  }

  const bool cL = lane < MM;
  const bool cR = lane >= MM && lane < 2*MM;
  const float u_l = u_in[s*MM + (cL ? lane : 0)];
  const float t1_l = alpha * (u_l - beta) * (u_l - beta);

  float col[MM];
#pragma unroll
  for (int i = 0; i < MM; ++i) {
    float du = urv[i] - u_l;
    float cv = kv * __expf(-t1v[i] - gamma*du*du - t1_l);
    float idv = (lane - MM == i) ? 1.f : 0.f;
    col[i] = cL ? cv : (cR ? idv : 0.f);
    if (cL) out[OFF_COV + (long long)s*400 + i*MM + lane] = cv;
  }

#pragma unroll
  for (int k = 0; k < MM; ++k) {
    float fc[MM];
#pragma unroll
    for (int i = 0; i < MM; ++i)
      fc[i] = __int_as_float(__builtin_amdgcn_readlane(__float_as_int(col[i]), k));
    const float pr = 1.0f / fc[k];
    col[k] *= pr;
#pragma unroll
    for (int i = 0; i < MM; ++i)
      if (i != k) col[i] = fmaf(-fc[i], col[k], col[i]);
  }

  if (cR) {
    const int t = lane - MM;
#pragma unroll
    for (int i = 0; i < MM; ++i)
      out[OFF_INV + (long long)s*400 + i*MM + t] = col[i];
  }

  float dotr = 0.f;
#pragma unroll
  for (int i = 0; i < MM; ++i) dotr += rv_[i] * col[i];
  float mpart = cR ? dotr * mean_u[s*MM + (lane - MM)] : 0.f;
  float mu = mpart;
#pragma unroll
  for (int o = 1; o < 64; o <<= 1) mu += __shfl_xor(mu, o, 64);
  mu = rfl(mu);
  if (lane == 0) g_mu[s] = mu;

  __shared__ float Lm[MM][MM];
  for (int c = lane; c < MM*MM; c += 64) Lm[c/MM][c%MM] = 0.f;
  __syncthreads();
  for (int k = lane; k < TRI; k += 64) {
    int i = (int)((sqrtf(8.f*(float)k + 1.f) - 1.f) * 0.5f);
    while ((i+1)*(i+2)/2 <= k) ++i;
    while (i*(i+1)/2 > k) --i;
    int jx = k - i*(i+1)/2;
    Lm[i][jx] = su_low[s*TRI + k];
  }
  __syncthreads();
  for (int c = lane; c < MM*MM; c += 64) {
    int i = c / MM, kk = c % MM;
    float acc = 0.f;
#pragma unroll
    for (int jx = 0; jx < MM; ++jx) acc += Lm[i][jx] * Lm[kk][jx];
    out[OFF_SU + (long long)s*400 + c] = acc;
  }

  if (cL) {
    out[OFF_MEANU + s*MM + lane] = mean_u[s*MM + lane];
    out[OFF_UIN  + s*MM + lane] = u_l;
  }

  {
    long long base = (s < NSUB) ? (OFF_FE + (long long)s*NFILT)
                                : (OFF_FI + (long long)(s - NSUB)*NFILT);
    float2 f2 = make_float2(mu, mu);
    float2* dst = (float2*)(out + base);
    for (int n = lane; n < NFILT/2; n += 64) dst[n] = f2;
  }

  if (s == 0) {
    if (lane < 16) {
      g_W[lane]  = __expf(W_log[lane]);
      g_Th[lane] = Theta[lane];
    }
    if (lane == 0) g_Vo = V_o_p[0];
  }
}

// ---------------------------------------------------------------------------
// k_scan: 2000 blocks x 256 threads. DENSE float4 loads (fi = 256k + tid,
// lane-consecutive), mu-fold per fixed quarter (tid&3), bounce through a
// [256][17]-padded LDS tile (stride-17 b32: 2-way bank aliasing = free),
// then row-per-thread DPP scan (validated) + cross-wave prefix.
// Stores go to TRANSPOSED S_t[c][T]: per-instruction 64 consecutive words.
// ---------------------------------------------------------------------------
__global__ void __launch_bounds__(256, 8)
k_scan(const float4* __restrict__ E4, const float4* __restrict__ I4,
       float* __restrict__ St, float* __restrict__ G, int T)
{
  __shared__ float tile[256*17 + 4];
  __shared__ float wred[4][16];
  const int tid  = threadIdx.x;    // 0..255
  const int lane = tid & 63;
  const int w    = tid >> 6;       // 0..3
  const int qg   = tid & 3;        // this thread's channel quarter
  const int b    = blockIdx.x;

  const float4 mue4 = *(const float4*)&g_mu[4*qg];
  const float4 mui4 = *(const float4*)&g_mu[16 + 4*qg];
  const float4 z4 = make_float4(0.f, 0.f, 0.f, 0.f);

  const long long base4 = (long long)b * (GR*4);   // float4 index of block start
  const long long q4tot = (long long)T * 4;

  // dense loads, all issued up front
  float4 ebuf[4], ibuf[4];
#pragma unroll
  for (int k = 0; k < 4; ++k) {
    const int fi = 256*k + tid;
    const long long gq = base4 + fi;
    const bool a = (fi < GR*4) && (gq < q4tot);
    ebuf[k] = a ? E4[gq] : z4;
    ibuf[k] = a ? I4[gq] : z4;
  }
  // fold + LDS tile writes (b32, stride-17 rows -> conflict-free)
#pragma unroll
  for (int k = 0; k < 4; ++k) {
    const int fi = 256*k + tid;
    const int row = fi >> 2;         // 0..255
    float* dst = &tile[row*17 + 4*qg];
    dst[0] = mue4.x*ebuf[k].x + mui4.x*ibuf[k].x;
    dst[1] = mue4.y*ebuf[k].y + mui4.y*ibuf[k].y;
    dst[2] = mue4.z*ebuf[k].z + mui4.z*ibuf[k].z;
    dst[3] = mue4.w*ebuf[k].w + mui4.w*ibuf[k].w;
  }
  __syncthreads();

  // row-per-thread: 16 conflict-free b32 reads, then DPP scans
  float inc[16];
#pragma unroll
  for (int c = 0; c < 16; ++c) {
    inc[c] = wave_incl_scan(tile[tid*17 + c]);
    if (lane == 63) wred[w][c] = inc[c];
  }
  __syncthreads();

  // cross-wave exclusive prefix (LDS broadcast reads)
  float sv[16];
#pragma unroll
  for (int q = 0; q < 4; ++q) {
    float ox = 0.f, oy = 0.f, oz = 0.f, ow = 0.f;
#pragma unroll
    for (int wp = 0; wp < 3; ++wp) {
      if (wp < w) {
        const float4 t = *(const float4*)&wred[wp][4*q];
        ox += t.x; oy += t.y; oz += t.z; ow += t.w;
      }
    }
    sv[4*q]   = inc[4*q]   + ox;
    sv[4*q+1] = inc[4*q+1] + oy;
    sv[4*q+2] = inc[4*q+2] + oz;
    sv[4*q+3] = inc[4*q+3] + ow;
  }

  // transposed stores: fixed c -> 64 consecutive words per instruction
  const long long r = (long long)b*GR + tid;
  if ((tid < GR) && (r < T)) {
#pragma unroll
    for (int c = 0; c < 16; ++c)
      St[(long long)c*T + r] = sv[c];
  }

  if (tid < 16) {
    float a = 0.f;
#pragma unroll
    for (int wp = 0; wp < 4; ++wp) a += wred[wp][tid];
    G[b*16 + tid] = a;
  }
}

// ---------------------------------------------------------------------------
// k_volt: pure elementwise, row-per-thread, DENSE loads via transposed S_t:
// d[c] = St[c*T + r] - St[c*T + r-2000]; both streams lane-consecutive and
// L2-local (scan-blocks b and b-8 share b%8 -> same XCD). Base table from G,
// tanh chain, dense store.
// ---------------------------------------------------------------------------
__global__ void __launch_bounds__(256, 8)
k_volt(const float* __restrict__ St, const float* __restrict__ G,
       float* __restrict__ out, int T)
{
  __shared__ float bs0[16];
  const int tid = threadIdx.x;     // 0..255
  const int b   = blockIdx.x;
  const long long r = (long long)b*GR + tid;
  const bool act = (tid < GR) && (r < T);
  const long long l = r - NFILT;
  const bool vl = act && (l >= 0);

  if (tid < 16) {
    float a = g_Th[tid];
#pragma unroll
    for (int gg = 0; gg < 8; ++gg) {
      const int gi = b - 8 + gg;
      if (gi >= 0) a += G[gi*16 + tid];
    }
    bs0[tid] = a;
  }

  float d[16];
#pragma unroll
  for (int c = 0; c < 16; ++c) {
    const long long cb = (long long)c * T;
    const float cu = act ? St[cb + r] : 0.f;
    const float lg = vl  ? St[cb + l] : 0.f;
    d[c] = cu - lg;
  }
  __syncthreads();

  float wk[16];
#pragma unroll
  for (int k = 0; k < 16; ++k) wk[k] = rfl(g_W[k]);
  const float Vo = rfl(g_Vo);

  float Wv[16];
#pragma unroll
  for (int q = 0; q < 4; ++q) {
    const float4 bsq = *(const float4*)&bs0[4*q];
    Wv[4*q]   = bsq.x + d[4*q];
    Wv[4*q+1] = bsq.y + d[4*q+1];
    Wv[4*q+2] = bsq.z + d[4*q+2];
    Wv[4*q+3] = bsq.w + d[4*q+3];
  }

  float v = ftanh(Wv[15]);
#pragma unroll
  for (int idx = 14; idx >= 0; --idx)
    v = ftanh(Wv[idx] + wk[idx + 1] * v);

  if (act) out[r] = v * wk[0] + Vo;
}

extern "C" void kernel_launch(void* const* d_in, const int* in_sizes, int n_in,
                              void* d_out, int out_size, void* d_ws, size_t ws_size,
                              hipStream_t stream) {
  const float* S_e       = (const float*)d_in[0];
  const float* S_i       = (const float*)d_in[1];
  const float* alpha_log = (const float*)d_in[2];
  const float* beta      = (const float*)d_in[3];
  const float* gamma_log = (const float*)d_in[4];
  const float* kvlog     = (const float*)d_in[5];
  const float* mean_u    = (const float*)d_in[6];
  const float* su_low    = (const float*)d_in[7];
  const float* u_in      = (const float*)d_in[8];
  const float* W_log     = (const float*)d_in[9];
  const float* V_o       = (const float*)d_in[10];
  const float* Theta     = (const float*)d_in[11];
  (void)n_in; (void)out_size; (void)ws_size;

  int T = in_sizes[0] / NSUB;
  const int nG = (T + GR - 1) / GR;

  // d_ws layout: S_t (f32, 16 channels x T, channel-major) then G (nG x 16 f32)
  float* St  = (float*)d_ws;
  float* G   = (float*)((char*)d_ws + (size_t)T * 64);
  float* out = (float*)d_out;

  hipLaunchKernelGGL(k_setup, dim3(32), dim3(64), 0, stream,
                     alpha_log, beta, gamma_log, kvlog, mean_u, su_low, u_in,
                     W_log, V_o, Theta, out, T);
  hipLaunchKernelGGL(k_scan, dim3(nG), dim3(256), 0, stream,
                     (const float4*)S_e, (const float4*)S_i, St, G, T);
  hipLaunchKernelGGL(k_volt, dim3(nG), dim3(256), 0, stream,
                     (const float*)St, G, out, T);
}